// Round 1
// baseline (598.968 us; speedup 1.0000x reference)
//
#include <hip/hip_runtime.h>

#define DIM 512
#define HID 2048
#define NE 8

typedef _Float16 half8v __attribute__((ext_vector_type(8)));
typedef _Float16 half4v __attribute__((ext_vector_type(4)));
typedef float f32x4 __attribute__((ext_vector_type(4)));

__device__ __forceinline__ void gload16(const void* g, void* l) {
  __builtin_amdgcn_global_load_lds(
      (const __attribute__((address_space(1))) void*)g,
      (__attribute__((address_space(3))) void*)l, 16, 0, 0);
}

// ---------------- cast fp32 -> fp16 (vectorized) ----------------
__global__ void k_cast_fp16(const float* __restrict__ src, _Float16* __restrict__ dst, int n4) {
  int i = blockIdx.x * blockDim.x + threadIdx.x;
  int stride = gridDim.x * blockDim.x;
  for (; i < n4; i += stride) {
    float4 v = ((const float4*)src)[i];
    half4v h = { (_Float16)v.x, (_Float16)v.y, (_Float16)v.z, (_Float16)v.w };
    ((half4v*)dst)[i] = h;
  }
}

// ---------------- transpose + cast: src fp32 [z][R][C] -> dst fp16 [z][C][R] ----------------
__global__ void k_transpose_cast(const float* __restrict__ src, _Float16* __restrict__ dst,
                                 int R, int C) {
  __shared__ _Float16 ts[64][66];
  int z = blockIdx.z;
  src += (size_t)z * R * C;
  dst += (size_t)z * R * C;
  int c0 = blockIdx.x * 64, r0 = blockIdx.y * 64;
  int t = threadIdx.x;
  int rr = t >> 4, cc = (t & 15) * 4;
  #pragma unroll
  for (int i = 0; i < 4; i++) {
    int row = rr + i * 16;
    float4 v = *(const float4*)&src[(size_t)(r0 + row) * C + c0 + cc];
    ts[row][cc + 0] = (_Float16)v.x; ts[row][cc + 1] = (_Float16)v.y;
    ts[row][cc + 2] = (_Float16)v.z; ts[row][cc + 3] = (_Float16)v.w;
  }
  __syncthreads();
  int cr = t >> 4, rb = (t & 15) * 4;
  #pragma unroll
  for (int i = 0; i < 4; i++) {
    int c = cr + i * 16;
    half4v o = { ts[rb + 0][c], ts[rb + 1][c], ts[rb + 2][c], ts[rb + 3][c] };
    *(half4v*)&dst[(size_t)(c0 + c) * R + r0 + rb] = o;
  }
}

// ---------------- router: fp32 logits, top-2 softmax, build per-expert lists ----------------
#define RT_TOK 16
__global__ void k_router(const float* __restrict__ x, const float* __restrict__ gw,
                         int* __restrict__ counts, int* __restrict__ perm,
                         float* __restrict__ pgate, int T) {
  __shared__ float xs[RT_TOK][520];
  __shared__ float gwt[8][520];
  __shared__ float lg[RT_TOK][8];
  int t = threadIdx.x;                 // 128 threads
  int tk0 = blockIdx.x * RT_TOK;
  for (int i = t; i < DIM * NE; i += 128) {
    int k = i >> 3, e = i & 7;
    gwt[e][k] = gw[i];
  }
  for (int i = t; i < RT_TOK * (DIM / 4); i += 128) {
    int row = i / (DIM / 4); int c4 = i % (DIM / 4);
    float4 v = *(const float4*)&x[(size_t)(tk0 + row) * DIM + c4 * 4];
    xs[row][c4 * 4 + 0] = v.x; xs[row][c4 * 4 + 1] = v.y;
    xs[row][c4 * 4 + 2] = v.z; xs[row][c4 * 4 + 3] = v.w;
  }
  __syncthreads();
  int tok = t >> 3, e = t & 7;
  float acc = 0.f;
  for (int k = 0; k < DIM; k += 4) {
    float4 xv = *(const float4*)&xs[tok][k];
    float4 wv = *(const float4*)&gwt[e][k];
    acc += xv.x * wv.x + xv.y * wv.y + xv.z * wv.z + xv.w * wv.w;
  }
  lg[tok][e] = acc;
  __syncthreads();
  if (t < RT_TOK) {
    float v0 = -1e30f, v1 = -1e30f; int i0 = 0, i1 = 0;
    #pragma unroll
    for (int j = 0; j < 8; j++) { float v = lg[t][j]; if (v > v0) { v0 = v; i0 = j; } }
    #pragma unroll
    for (int j = 0; j < 8; j++) { if (j == i0) continue; float v = lg[t][j]; if (v > v1) { v1 = v; i1 = j; } }
    float g0 = 1.f / (1.f + __expf(v1 - v0));
    float g1 = 1.f - g0;
    int token = tk0 + t;
    int p0 = atomicAdd(&counts[i0], 1);
    perm[i0 * T + p0] = token; pgate[i0 * T + p0] = g0;
    int p1 = atomicAdd(&counts[i1], 1);
    perm[i1 * T + p1] = token; pgate[i1 * T + p1] = g1;
  }
}

__global__ void k_offsets(const int* __restrict__ counts, int* __restrict__ offsets) {
  if (threadIdx.x == 0) {
    int s = 0;
    for (int e = 0; e < 8; e++) { offsets[e] = s; s += counts[e]; }
  }
}

// ---------------- MFMA GEMM: 128x128 tile, BK=32, 4 waves, global_load_lds staging ----------
// MODE 0: fc1 -> gelu -> h (fp16).  MODE 1: fc2 -> plain store (master).
// MODE 2: fc2 -> gated atomicAdd (experts).
template<int K, int MODE>
__global__ __launch_bounds__(256) void k_gemm(
    const _Float16* __restrict__ A,    // rows of length K
    const _Float16* __restrict__ Bt,   // [e][N][K] fp16 (pre-transposed)
    const float* __restrict__ bias,    // + e*bias_stride
    int bias_stride,
    const int* __restrict__ counts,    // null -> count_fixed
    int count_fixed,
    const int* __restrict__ offsets,   // null -> 0 (h row base)
    const int* __restrict__ perm,      // null -> identity (+ e*T)
    const float* __restrict__ pgate,   // MODE2 gates (+ e*T)
    _Float16* __restrict__ hout,       // MODE0 dest [*, HID]
    float* __restrict__ out,           // MODE1/2 dest [*, DIM]
    int T) {
  constexpr int N = (MODE == 0) ? HID : DIM;
  int e = blockIdx.z;
  int count = counts ? counts[e] : count_fixed;
  int m0 = blockIdx.x * 128;
  if (m0 >= count) return;
  int n0 = blockIdx.y * 128;
  int hbase = offsets ? offsets[e] : 0;
  const _Float16* Be = Bt + (size_t)e * N * K;
  const float* be = bias + (size_t)e * bias_stride;

  __shared__ _Float16 As[128 * 32];
  __shared__ _Float16 Bs[128 * 32];

  int t = threadIdx.x;
  int lane = t & 63;
  int wid = t >> 6;
  int wm = (wid & 1) * 64, wn = (wid >> 1) * 64;

  const char* aSrc[2]; const char* bSrc[2];
  #pragma unroll
  for (int i = 0; i < 2; i++) {
    int s = t + i * 256;
    int r = s >> 2, ch = s & 3;
    int pos = m0 + r; int pr = pos < count ? pos : count - 1;
    int arow;
    if (MODE == 0) arow = perm ? perm[e * T + pr] : pr;
    else           arow = hbase + pr;
    aSrc[i] = (const char*)(A + (size_t)arow * K) + ch * 16;
    bSrc[i] = (const char*)(Be + (size_t)(n0 + r) * K) + ch * 16;
  }

  f32x4 acc[4][4] = {};

  for (int kt = 0; kt < K / 32; ++kt) {
    gload16(aSrc[0], (char*)As + t * 16);
    gload16(aSrc[1], (char*)As + t * 16 + 4096);
    gload16(bSrc[0], (char*)Bs + t * 16);
    gload16(bSrc[1], (char*)Bs + t * 16 + 4096);
    aSrc[0] += 64; aSrc[1] += 64; bSrc[0] += 64; bSrc[1] += 64;
    __syncthreads();
    half8v af[4], bf[4];
    #pragma unroll
    for (int mi = 0; mi < 4; mi++)
      af[mi] = *(const half8v*)&As[(wm + mi * 16 + (lane & 15)) * 32 + (lane >> 4) * 8];
    #pragma unroll
    for (int ni = 0; ni < 4; ni++)
      bf[ni] = *(const half8v*)&Bs[(wn + ni * 16 + (lane & 15)) * 32 + (lane >> 4) * 8];
    #pragma unroll
    for (int mi = 0; mi < 4; mi++)
      #pragma unroll
      for (int ni = 0; ni < 4; ni++)
        acc[mi][ni] = __builtin_amdgcn_mfma_f32_16x16x32_f16(af[mi], bf[ni], acc[mi][ni], 0, 0, 0);
    __syncthreads();
  }

  int cl = lane & 15, rh = (lane >> 4) * 4;
  float bv[4];
  #pragma unroll
  for (int ni = 0; ni < 4; ni++) bv[ni] = be[n0 + wn + ni * 16 + cl];
  #pragma unroll
  for (int mi = 0; mi < 4; mi++) {
    #pragma unroll
    for (int r = 0; r < 4; r++) {
      int pos = m0 + wm + mi * 16 + rh + r;
      if (pos >= count) continue;
      int orow; float g = 1.f;
      if (MODE == 0) orow = hbase + pos;
      else {
        orow = perm ? perm[e * T + pos] : pos;
        if (MODE == 2) g = pgate[e * T + pos];
      }
      #pragma unroll
      for (int ni = 0; ni < 4; ni++) {
        float v = acc[mi][ni][r] + bv[ni];
        int col = n0 + wn + ni * 16 + cl;
        if (MODE == 0) {
          // jax.nn.gelu approximate=True: x*sigmoid(2*sqrt(2/pi)*(x+0.044715x^3))
          float ge = v / (1.f + __expf(-1.5957691216057308f * (v + 0.044715f * v * v * v)));
          hout[(size_t)orow * HID + col] = (_Float16)ge;
        } else if (MODE == 1) {
          out[(size_t)orow * DIM + col] = v;
        } else {
          unsafeAtomicAdd(&out[(size_t)orow * DIM + col], g * v);
        }
      }
    }
  }
}

extern "C" void kernel_launch(void* const* d_in, const int* in_sizes, int n_in,
                              void* d_out, int out_size, void* d_ws, size_t ws_size,
                              hipStream_t stream) {
  const float* x         = (const float*)d_in[0];
  const float* gate_w    = (const float*)d_in[1];
  const float* master_w1 = (const float*)d_in[2];
  const float* master_b1 = (const float*)d_in[3];
  const float* master_w2 = (const float*)d_in[4];
  const float* master_b2 = (const float*)d_in[5];
  const float* expert_w1 = (const float*)d_in[6];
  const float* expert_b1 = (const float*)d_in[7];
  const float* expert_w2 = (const float*)d_in[8];
  const float* expert_b2 = (const float*)d_in[9];
  float* out = (float*)d_out;
  int T = in_sizes[0] / DIM;   // 16384 tokens

  // ---- workspace layout (~190 MB) ----
  char* p = (char*)d_ws;
  _Float16* xb   = (_Float16*)p; p += (size_t)T * DIM * 2;
  _Float16* wb1t = (_Float16*)p; p += (size_t)9 * HID * DIM * 2;  // [e][HID][DIM], master=8
  _Float16* wb2t = (_Float16*)p; p += (size_t)9 * DIM * HID * 2;  // [e][DIM][HID], master=8
  int*   counts  = (int*)p;      p += 256;
  int*   offsets = (int*)p;      p += 256;
  int*   perm    = (int*)p;      p += (size_t)8 * T * 4;
  float* pgate   = (float*)p;    p += (size_t)8 * T * 4;
  _Float16* hbuf = (_Float16*)p; p += (size_t)2 * T * HID * 2;    // 2T rows (master reuses [0,T))

  hipMemsetAsync(counts, 0, 64, stream);

  k_cast_fp16<<<1024, 256, 0, stream>>>(x, xb, T * DIM / 4);

  k_transpose_cast<<<dim3(HID / 64, DIM / 64, 8), 256, 0, stream>>>(expert_w1, wb1t, DIM, HID);
  k_transpose_cast<<<dim3(HID / 64, DIM / 64, 1), 256, 0, stream>>>(master_w1, wb1t + (size_t)8 * HID * DIM, DIM, HID);
  k_transpose_cast<<<dim3(DIM / 64, HID / 64, 8), 256, 0, stream>>>(expert_w2, wb2t, HID, DIM);
  k_transpose_cast<<<dim3(DIM / 64, HID / 64, 1), 256, 0, stream>>>(master_w2, wb2t + (size_t)8 * DIM * HID, HID, DIM);

  k_router<<<T / RT_TOK, 128, 0, stream>>>(x, gate_w, counts, perm, pgate, T);
  k_offsets<<<1, 64, 0, stream>>>(counts, offsets);

  // master: fc1 -> gelu -> h ; fc2 -> store
  k_gemm<DIM, 0><<<dim3(T / 128, HID / 128, 1), 256, 0, stream>>>(
      xb, wb1t + (size_t)8 * HID * DIM, master_b1, 0, nullptr, T, nullptr, nullptr, nullptr,
      hbuf, nullptr, T);
  k_gemm<HID, 1><<<dim3(T / 128, DIM / 128, 1), 256, 0, stream>>>(
      hbuf, wb2t + (size_t)8 * DIM * HID, master_b2, 0, nullptr, T, nullptr, nullptr, nullptr,
      nullptr, out, T);

  // experts: fused over z=8, early-exit past counts[e]
  k_gemm<DIM, 0><<<dim3(T / 128, HID / 128, 8), 256, 0, stream>>>(
      xb, wb1t, expert_b1, HID, counts, 0, offsets, perm, nullptr,
      hbuf, nullptr, T);
  k_gemm<HID, 2><<<dim3(T / 128, DIM / 128, 8), 256, 0, stream>>>(
      hbuf, wb2t, expert_b2, DIM, counts, 0, offsets, perm, pgate,
      nullptr, out, T);
}